// Round 8
// baseline (400.633 us; speedup 1.0000x reference)
//
#include <hip/hip_runtime.h>
#include <cfloat>

// Problem constants: inputs (64,256,512) fp32, emb (1024,512) fp32.
#define NROWS  16384          // 64*256
#define DIM    512
#define KC     1024
#define QELEMS (NROWS * DIM)  // 8388608
// d_out layout (fp32): [0]=loss, [1 .. QELEMS]=quantized, [1+QELEMS .. +NROWS]=indices (as float)

#define NSPLIT 16             // one block per 64-code column tile (was 8/128)
#define CHUNKS 130            // A kq-plane stride in 16B chunks (128 rows + 2 pad)
#define ECHUNKS 66            // E kq-plane stride (64 rows + 2 pad)
// Bank math (round-3 counter-backed): stage write chunk = skq*STRIDE + row;
// bank = (chunk*4) mod 32. 130*4 mod 32 = 8 and 66*4 mod 32 = 8 -> the four
// skq planes start 8 banks apart; a quarter-wave's 16 lanes hit 16 distinct
// banks -> conflict-free writes. Fragment reads (16 contiguous chunks per
// quarter-wave, 8 lanes per 4-bank group) are even -> no excess conflicts.

// ROUND 7 = infra failure ("container failed twice": no compile error, no
// pass/fail, no counters). Kernel re-audited for hang/fault classes: uniform
// barriers only, all global/LDS accesses in-bounds, legal launch_bounds.
// RESUBMITTING UNCHANGED (single-variable discipline: the NSPLIT=16
// experiment has not actually run yet).

typedef float  floatx4 __attribute__((ext_vector_type(4)));
typedef _Float16 half8 __attribute__((ext_vector_type(8)));
typedef _Float16 half4 __attribute__((ext_vector_type(4)));

// ROUND-6 POST-MORTEM: single-buffer + lgkm-only KBARRIER + 3-4 blocks/CU gave
// the first real win (77.0 -> 73.1us, occupancy 19.5 -> 24.5%). Model update:
// per kt-round, MFMA demand ~1.9k cyc and LDS ~1.9k cyc vs ~5.5k measured ->
// still phase-convoy-bound: a block's waves march in lockstep between the two
// barriers, and ~2 effectively-resident blocks/CU can't fill each other's
// gaps. The proven lever is MORE independently-phased resident blocks.
// THIS ROUND: NSPLIT 8->16 (64-code tiles). Per block: E-tile halves, per-kt
// MFMA halves (24), staging 6 stores/thread. Reduction scratch UNIONED onto
// the E staging arrays (dead after the K-loop; KBARRIER separates) -> LDS
// 24.5KB -> 6 blocks/CU; VGPR ~80 fits the 84 cap of __launch_bounds__(256,6)
// (round-6 kernel fit 84 with more live state). Grid 2048 -> ~6 resident
// blocks/CU, 6 waves/SIMD of independent phase (3x round-6 diversity).
// Cost accepted: fragment reads amortize worse (12 reads / 24 MFMA), LDS read
// traffic +50% from a ~35%-busy pipe. A-tile sharers (16 bn) still co-XCD via
// bm-in-low-bits; per-XCD A working set unchanged (4MB = L2).
// Numerics: identical values, identical 3-pass MFMA order per acc element
// (hi*bh, hi*bl, lo*bh) -> bit-identical. Score keeps the PASSING structure:
// s = fl( fl(sqx+sqe) - acc*2^-26 ).
#define KBARRIER() do { \
    asm volatile("s_waitcnt lgkmcnt(0)" ::: "memory"); \
    __builtin_amdgcn_s_barrier(); \
} while (0)

// ---------------- kernel 1: fused prep (A and E) ----------------
// blocks [0,4096): A rows; [4096,4352): E rows. rowsq tree + split math VERBATIM
// from the passing rounds (part of the verified rounding structure).
__global__ __launch_bounds__(256) void prep_kernel(const float* __restrict__ A,
                                                   const float* __restrict__ E,
                                                   float* __restrict__ xsq,
                                                   float* __restrict__ esq,
                                                   _Float16* __restrict__ ah,
                                                   _Float16* __restrict__ al,
                                                   _Float16* __restrict__ eh,
                                                   _Float16* __restrict__ el,
                                                   unsigned long long* __restrict__ packed,
                                                   float* __restrict__ out) {
    if (blockIdx.x == 0 && threadIdx.x == 0) out[0] = 0.f;
    const int wave = threadIdx.x >> 6, lane = threadIdx.x & 63;
    const bool isA = blockIdx.x < (NROWS / 4);
    const int row = (isA ? blockIdx.x : blockIdx.x - NROWS / 4) * 4 + wave;
    const float* M = isA ? A : E;
    const float scale = isA ? 2048.0f : 65536.0f;

    const float4* Mr = (const float4*)(M + (size_t)row * DIM);
    float4 va = Mr[lane];
    float4 vb = Mr[lane + 64];
    float s = 0.f;
    s += va.x*va.x + va.y*va.y + va.z*va.z + va.w*va.w;   // same tree as rowsq i=0
    s += vb.x*vb.x + vb.y*vb.y + vb.z*vb.z + vb.w*vb.w;   // i=1
    #pragma unroll
    for (int off = 32; off; off >>= 1) s += __shfl_down(s, off, 64);
    if (lane == 0) {
        if (isA) { xsq[row] = s; packed[row] = ~0ULL; }
        else     { esq[row] = s; }
    }

    float xa[4] = {va.x, va.y, va.z, va.w}, xb[4] = {vb.x, vb.y, vb.z, vb.w};
    half4 ha, la, hb, lb;
    #pragma unroll
    for (int e = 0; e < 4; ++e) {
        float t = xa[e] * scale;
        _Float16 h = (_Float16)t;
        ha[e] = h; la[e] = (_Float16)(t - (float)h);
        t = xb[e] * scale;
        h = (_Float16)t;
        hb[e] = h; lb[e] = (_Float16)(t - (float)h);
    }
    _Float16* hr = (isA ? ah : eh) + (size_t)row * DIM;
    _Float16* lr = (isA ? al : el) + (size_t)row * DIM;
    ((half4*)hr)[lane]      = ha;
    ((half4*)lr)[lane]      = la;
    ((half4*)hr)[lane + 64] = hb;
    ((half4*)lr)[lane + 64] = lb;
}

// ---------------- kernel 2: MFMA distance GEMM + fused argmin ----------------
// staging per thread (6 slots): A rows srow, srow+64 (hi+lo) + E row srow (hi+lo)
#define LOAD_SET(S, koff) \
    S##A0 = *(const half8*)(gA  + (koff)); \
    S##A1 = *(const half8*)(gA  + 64 * DIM + (koff)); \
    S##L0 = *(const half8*)(gAl + (koff)); \
    S##L1 = *(const half8*)(gAl + 64 * DIM + (koff)); \
    S##E0 = *(const half8*)(gE  + (koff)); \
    S##F0 = *(const half8*)(gEl + (koff));

#define STORE_SET(S) \
    AhT[cw0] = S##A0; AhT[cw1] = S##A1; \
    AlT[cw0] = S##L0; AlT[cw1] = S##L1; \
    EhT[cwe] = S##E0; ElT[cwe] = S##F0;

#define COMPUTE() { \
    half8 fa[4], fbh[2], fbl[2]; \
    _Pragma("unroll") \
    for (int i = 0; i < 4; ++i) \
        fa[i] = AhT[qd * CHUNKS + wm * 64 + i * 16 + tx]; \
    _Pragma("unroll") \
    for (int j = 0; j < 2; ++j) { \
        fbh[j] = EhT[qd * ECHUNKS + wn * 32 + j * 16 + tx]; \
        fbl[j] = ElT[qd * ECHUNKS + wn * 32 + j * 16 + tx]; \
    } \
    __builtin_amdgcn_s_setprio(1); \
    _Pragma("unroll") \
    for (int i = 0; i < 4; ++i) \
        _Pragma("unroll") \
        for (int j = 0; j < 2; ++j) \
            acc[i][j] = __builtin_amdgcn_mfma_f32_16x16x32_f16(fa[i], fbh[j], acc[i][j], 0, 0, 0); \
    _Pragma("unroll") \
    for (int i = 0; i < 4; ++i) \
        _Pragma("unroll") \
        for (int j = 0; j < 2; ++j) \
            acc[i][j] = __builtin_amdgcn_mfma_f32_16x16x32_f16(fa[i], fbl[j], acc[i][j], 0, 0, 0); \
    __builtin_amdgcn_s_setprio(0); \
    _Pragma("unroll") \
    for (int i = 0; i < 4; ++i) \
        fa[i] = AlT[qd * CHUNKS + wm * 64 + i * 16 + tx]; \
    __builtin_amdgcn_s_setprio(1); \
    _Pragma("unroll") \
    for (int i = 0; i < 4; ++i) \
        _Pragma("unroll") \
        for (int j = 0; j < 2; ++j) \
            acc[i][j] = __builtin_amdgcn_mfma_f32_16x16x32_f16(fa[i], fbh[j], acc[i][j], 0, 0, 0); \
    __builtin_amdgcn_s_setprio(0); \
}

__global__ __launch_bounds__(256, 6) void mfma_argmin_kernel(const _Float16* __restrict__ ah,
                                                             const _Float16* __restrict__ al,
                                                             const _Float16* __restrict__ eh,
                                                             const _Float16* __restrict__ el,
                                                             const float* __restrict__ esq,
                                                             const float* __restrict__ xsq,
                                                             unsigned long long* __restrict__ packed) {
    __shared__ half8 AhT[4 * CHUNKS], AlT[4 * CHUNKS];     // 16.25KB (A: 128 rows)
    __shared__ half8 EhT[4 * ECHUNKS], ElT[4 * ECHUNKS];   // 8.25KB  (E: 64 rows)
    // reduction scratch UNIONED onto E staging (dead after K-loop; KBARRIER
    // separates last tile read from first redv write). redv/redi: 128 rows x 2 wn.
    float* redv = (float*)&EhT[0];                          // 1KB of 4.1KB
    int*   redi = (int*)&ElT[0];                            // 1KB of 4.1KB

    const int tid = threadIdx.x;
    const int lane = tid & 63, wave = tid >> 6;
    const int wm = wave >> 1, wn = wave & 1;      // 2x2 wave grid; per-wave 64x32
    const int tx = lane & 15, qd = lane >> 4;
    const int bm = blockIdx.x & 127, bn = blockIdx.x >> 7;   // XCD swizzle: bm low
    const int m0 = bm * 128, c0 = bn * 64;

    // staging: thread t handles A rows (t>>2), (t>>2)+64 and E row (t>>2); kq=t&3
    const int srow = tid >> 2, skq = tid & 3;
    const _Float16* gA  = ah + (size_t)(m0 + srow) * DIM + skq * 8;
    const _Float16* gAl = al + (size_t)(m0 + srow) * DIM + skq * 8;
    const _Float16* gE  = eh + (size_t)(c0 + srow) * DIM + skq * 8;
    const _Float16* gEl = el + (size_t)(c0 + srow) * DIM + skq * 8;
    const int cw0 = skq * CHUNKS + srow, cw1 = cw0 + 64;    // A LDS chunk indices
    const int cwe = skq * ECHUNKS + srow;                   // E LDS chunk index

    floatx4 acc[4][2];
    #pragma unroll
    for (int i = 0; i < 4; ++i)
        #pragma unroll
        for (int j = 0; j < 2; ++j) acc[i][j] = (floatx4){0.f, 0.f, 0.f, 0.f};

    // one named staging set (rule #20: named regs, not runtime-indexed)
    half8 sA0, sA1, sL0, sL1, sE0, sF0;

    // prologue: tile0 -> LDS; tile1 -> regs, in flight across barrier + compute
    LOAD_SET(s, 0);
    STORE_SET(s);
    LOAD_SET(s, 32);

    #pragma unroll 1                               // spill guard
    for (int kt = 0; kt < 16; ++kt) {
        KBARRIER();                                // tile kt writes visible (lgkm only)
        COMPUTE();                                 // tile kt from LDS
        if (kt < 15) {
            KBARRIER();                            // all waves done READING tile kt
            STORE_SET(s);                          // tile kt+1 regs -> LDS
            if (kt < 14) { LOAD_SET(s, (kt + 2) * 32); }  // refill: in flight a full kt
        }
    }
    KBARRIER();                                    // tile reads done -> E LDS reusable

    // ---- epilogue: scores + argmin (identical arithmetic to passing rounds) ----
    float sqe_v[2];
    #pragma unroll
    for (int j = 0; j < 2; ++j) sqe_v[j] = esq[c0 + wn * 32 + j * 16 + tx];
    #pragma unroll
    for (int i = 0; i < 4; ++i) {
        #pragma unroll
        for (int r = 0; r < 4; ++r) {
            int rl = wm * 64 + i * 16 + qd * 4 + r;        // C/D: row = qd*4+reg
            float sx = xsq[m0 + rl];
            float bvv = FLT_MAX; int bii = 0x7fffffff;
            #pragma unroll
            for (int j = 0; j < 2; ++j) {
                float S = sx + sqe_v[j];                   // fl(sqx + sqe)
                float s = S - acc[i][j][r] * (1.0f / 67108864.0f);  // fl(S - 2m)
                int c = c0 + wn * 32 + j * 16 + tx;
                if (s < bvv || (s == bvv && c < bii)) { bvv = s; bii = c; }
            }
            #pragma unroll
            for (int md = 1; md < 16; md <<= 1) {
                float ov = __shfl_xor(bvv, md, 64);
                int   oc = __shfl_xor(bii, md, 64);
                if (ov < bvv || (ov == bvv && oc < bii)) { bvv = ov; bii = oc; }
            }
            if (tx == 0) { redv[rl * 2 + wn] = bvv; redi[rl * 2 + wn] = bii; }
        }
    }
    __syncthreads();
    if (tid < 128) {
        float v0 = redv[tid * 2 + 0], v1 = redv[tid * 2 + 1];
        int   i0 = redi[tid * 2 + 0], i1 = redi[tid * 2 + 1];
        float v = (v1 < v0) ? v1 : v0;            // tie -> wn0 (smaller col)
        int   ix = (v1 < v0) ? i1 : i0;
        // scores positive -> float bits monotonic; lexicographic (bits,idx) min
        // == np.argmin first-occurrence tie-break.
        unsigned long long pk = ((unsigned long long)__float_as_uint(v) << 32)
                              | (unsigned int)ix;
        atomicMin(&packed[m0 + tid], pk);
    }
}

// ---------------- kernel 3: indices + gather quantized + loss from scores ----------------
// loss = 1.25 * mean(min-score): the min score IS fl(||x-e||^2) to ~1e-4/row;
// summed error ~1e-7 << the output threshold. Saves re-reading A (33.5 MB).
// 1024 blocks x 16 rows (passed rounds 1-6): 256-block grid was 1 block/CU.
__global__ __launch_bounds__(256) void finalize_kernel(const float* __restrict__ E,
                                                       const unsigned long long* __restrict__ packed,
                                                       float* __restrict__ out) {
    float* q = out + 1;
    float* idxF = out + 1 + QELEMS;
    const int tid = threadIdx.x;
    const int r0 = blockIdx.x * 16;

    __shared__ int sidx[16];
    if (tid < 64) {                               // wave 0: unpack idx + score
        float sc = 0.f;
        if (tid < 16) {
            unsigned long long pk = packed[r0 + tid];
            int idx = (int)(unsigned int)(pk & 0xFFFFFFFFull);
            sc = __uint_as_float((unsigned int)(pk >> 32));
            sidx[tid] = idx;
            idxF[r0 + tid] = (float)idx;
        }
        #pragma unroll
        for (int off = 8; off; off >>= 1) sc += __shfl_down(sc, off, 16);
        if (tid == 0) atomicAdd(out, sc * (1.25f / (float)QELEMS));
    }
    __syncthreads();

    #pragma unroll 4
    for (int it = 0; it < 8; ++it) {              // 16 rows * 128 float4 = 2048 slots
        int flat = it * 256 + tid;
        int row = flat >> 7;
        int d4  = (flat & 127) * 4;
        int idx = sidx[row];
        float4 e = *(const float4*)(E + (size_t)idx * DIM + d4);
        *(float4*)(q + (size_t)(r0 + row) * DIM + d4) = e;
    }
}

extern "C" void kernel_launch(void* const* d_in, const int* in_sizes, int n_in,
                              void* d_out, int out_size, void* d_ws, size_t ws_size,
                              hipStream_t stream) {
    const float* A = (const float*)d_in[0];   // inputs (64,256,512)
    const float* E = (const float*)d_in[1];   // emb_weight (1024,512)
    float* out = (float*)d_out;

    unsigned long long* packed = (unsigned long long*)d_ws;     // 16384 u64
    float*    esq  = (float*)(packed + NROWS);                  // 1024
    float*    xsq  = esq + KC;                                  // 16384
    _Float16* eh   = (_Float16*)(xsq + NROWS);                  // 1024*512 (16B-aligned)
    _Float16* el   = eh + (size_t)KC * DIM;
    _Float16* ah   = el + (size_t)KC * DIM;                     // 16384*512
    _Float16* al   = ah + (size_t)NROWS * DIM;

    prep_kernel<<<NROWS / 4 + KC / 4, 256, 0, stream>>>(A, E, xsq, esq, ah, al, eh, el, packed, out);
    mfma_argmin_kernel<<<(NROWS / 128) * NSPLIT, 256, 0, stream>>>(
        ah, al, eh, el, esq, xsq, packed);
    finalize_kernel<<<NROWS / 16, 256, 0, stream>>>(E, packed, out);
}

// Round 9
// 183.606 us; speedup vs baseline: 2.1820x; 2.1820x over previous
//
#include <hip/hip_runtime.h>
#include <cfloat>

// Problem constants: inputs (64,256,512) fp32, emb (1024,512) fp32.
#define NROWS  16384          // 64*256
#define DIM    512
#define KC     1024
#define QELEMS (NROWS * DIM)  // 8388608
// d_out layout (fp32): [0]=loss, [1 .. QELEMS]=quantized, [1+QELEMS .. +NROWS]=indices (as float)

#define NSPLIT 16             // one block per 64-code column tile
#define CHUNKS 130            // A kq-plane stride in 16B chunks (128 rows + 2 pad)
#define ECHUNKS 66            // E kq-plane stride (64 rows + 2 pad)
// Bank math (round-3 counter-backed): stage write chunk = skq*STRIDE + row;
// bank = (chunk*4) mod 32. 130*4 mod 32 = 8 and 66*4 mod 32 = 8 -> the four
// skq planes start 8 banks apart; a quarter-wave's 16 lanes hit 16 distinct
// banks -> conflict-free writes. Fragment reads (16 contiguous chunks per
// quarter-wave) conflict-free.

// ROUND-8 POST-MORTEM: NSPLIT=16 ran but __launch_bounds__(256,6) caused
// catastrophic scratch spill: VGPR_Count=40 (vs ~106 live), WRITE_SIZE=724MB
// from a kernel that writes 128KB (pure spill), FETCH 450MB, 305us
// spill-BW-bound. Mechanism (m69): occupancy steps at VGPR={64,128,256} ->
// 8/4/2 waves/SIMD; there is NO 85-reg/6-wave step, so min-6-waves forced a
// <=64-VGPR clamp -> half the live state spilled to scratch every kt.
// The useful signal: occupancy DID hit 54% -> the geometry delivers block
// diversity; only the spill is broken.
// THIS ROUND: __launch_bounds__(256,4) -> cap 128 >= ~106 live -> no spill,
// 4 blocks/CU resident (16 waves, ~50% occ, 2x round-6 residency).
// Everything else byte-identical to round 8 (numerically PASSED even while
// spilling) -> bit-identical numerics.
#define KBARRIER() do { \
    asm volatile("s_waitcnt lgkmcnt(0)" ::: "memory"); \
    __builtin_amdgcn_s_barrier(); \
} while (0)

typedef float  floatx4 __attribute__((ext_vector_type(4)));
typedef _Float16 half8 __attribute__((ext_vector_type(8)));
typedef _Float16 half4 __attribute__((ext_vector_type(4)));

// ---------------- kernel 1: fused prep (A and E) ----------------
// blocks [0,4096): A rows; [4096,4352): E rows. rowsq tree + split math VERBATIM
// from the passing rounds (part of the verified rounding structure).
__global__ __launch_bounds__(256) void prep_kernel(const float* __restrict__ A,
                                                   const float* __restrict__ E,
                                                   float* __restrict__ xsq,
                                                   float* __restrict__ esq,
                                                   _Float16* __restrict__ ah,
                                                   _Float16* __restrict__ al,
                                                   _Float16* __restrict__ eh,
                                                   _Float16* __restrict__ el,
                                                   unsigned long long* __restrict__ packed,
                                                   float* __restrict__ out) {
    if (blockIdx.x == 0 && threadIdx.x == 0) out[0] = 0.f;
    const int wave = threadIdx.x >> 6, lane = threadIdx.x & 63;
    const bool isA = blockIdx.x < (NROWS / 4);
    const int row = (isA ? blockIdx.x : blockIdx.x - NROWS / 4) * 4 + wave;
    const float* M = isA ? A : E;
    const float scale = isA ? 2048.0f : 65536.0f;

    const float4* Mr = (const float4*)(M + (size_t)row * DIM);
    float4 va = Mr[lane];
    float4 vb = Mr[lane + 64];
    float s = 0.f;
    s += va.x*va.x + va.y*va.y + va.z*va.z + va.w*va.w;   // same tree as rowsq i=0
    s += vb.x*vb.x + vb.y*vb.y + vb.z*vb.z + vb.w*vb.w;   // i=1
    #pragma unroll
    for (int off = 32; off; off >>= 1) s += __shfl_down(s, off, 64);
    if (lane == 0) {
        if (isA) { xsq[row] = s; packed[row] = ~0ULL; }
        else     { esq[row] = s; }
    }

    float xa[4] = {va.x, va.y, va.z, va.w}, xb[4] = {vb.x, vb.y, vb.z, vb.w};
    half4 ha, la, hb, lb;
    #pragma unroll
    for (int e = 0; e < 4; ++e) {
        float t = xa[e] * scale;
        _Float16 h = (_Float16)t;
        ha[e] = h; la[e] = (_Float16)(t - (float)h);
        t = xb[e] * scale;
        h = (_Float16)t;
        hb[e] = h; lb[e] = (_Float16)(t - (float)h);
    }
    _Float16* hr = (isA ? ah : eh) + (size_t)row * DIM;
    _Float16* lr = (isA ? al : el) + (size_t)row * DIM;
    ((half4*)hr)[lane]      = ha;
    ((half4*)lr)[lane]      = la;
    ((half4*)hr)[lane + 64] = hb;
    ((half4*)lr)[lane + 64] = lb;
}

// ---------------- kernel 2: MFMA distance GEMM + fused argmin ----------------
// staging per thread (6 slots): A rows srow, srow+64 (hi+lo) + E row srow (hi+lo)
#define LOAD_SET(S, koff) \
    S##A0 = *(const half8*)(gA  + (koff)); \
    S##A1 = *(const half8*)(gA  + 64 * DIM + (koff)); \
    S##L0 = *(const half8*)(gAl + (koff)); \
    S##L1 = *(const half8*)(gAl + 64 * DIM + (koff)); \
    S##E0 = *(const half8*)(gE  + (koff)); \
    S##F0 = *(const half8*)(gEl + (koff));

#define STORE_SET(S) \
    AhT[cw0] = S##A0; AhT[cw1] = S##A1; \
    AlT[cw0] = S##L0; AlT[cw1] = S##L1; \
    EhT[cwe] = S##E0; ElT[cwe] = S##F0;

#define COMPUTE() { \
    half8 fa[4], fbh[2], fbl[2]; \
    _Pragma("unroll") \
    for (int i = 0; i < 4; ++i) \
        fa[i] = AhT[qd * CHUNKS + wm * 64 + i * 16 + tx]; \
    _Pragma("unroll") \
    for (int j = 0; j < 2; ++j) { \
        fbh[j] = EhT[qd * ECHUNKS + wn * 32 + j * 16 + tx]; \
        fbl[j] = ElT[qd * ECHUNKS + wn * 32 + j * 16 + tx]; \
    } \
    __builtin_amdgcn_s_setprio(1); \
    _Pragma("unroll") \
    for (int i = 0; i < 4; ++i) \
        _Pragma("unroll") \
        for (int j = 0; j < 2; ++j) \
            acc[i][j] = __builtin_amdgcn_mfma_f32_16x16x32_f16(fa[i], fbh[j], acc[i][j], 0, 0, 0); \
    _Pragma("unroll") \
    for (int i = 0; i < 4; ++i) \
        _Pragma("unroll") \
        for (int j = 0; j < 2; ++j) \
            acc[i][j] = __builtin_amdgcn_mfma_f32_16x16x32_f16(fa[i], fbl[j], acc[i][j], 0, 0, 0); \
    __builtin_amdgcn_s_setprio(0); \
    _Pragma("unroll") \
    for (int i = 0; i < 4; ++i) \
        fa[i] = AlT[qd * CHUNKS + wm * 64 + i * 16 + tx]; \
    __builtin_amdgcn_s_setprio(1); \
    _Pragma("unroll") \
    for (int i = 0; i < 4; ++i) \
        _Pragma("unroll") \
        for (int j = 0; j < 2; ++j) \
            acc[i][j] = __builtin_amdgcn_mfma_f32_16x16x32_f16(fa[i], fbh[j], acc[i][j], 0, 0, 0); \
    __builtin_amdgcn_s_setprio(0); \
}

__global__ __launch_bounds__(256, 4) void mfma_argmin_kernel(const _Float16* __restrict__ ah,
                                                             const _Float16* __restrict__ al,
                                                             const _Float16* __restrict__ eh,
                                                             const _Float16* __restrict__ el,
                                                             const float* __restrict__ esq,
                                                             const float* __restrict__ xsq,
                                                             unsigned long long* __restrict__ packed) {
    __shared__ half8 AhT[4 * CHUNKS], AlT[4 * CHUNKS];     // 16.25KB (A: 128 rows)
    __shared__ half8 EhT[4 * ECHUNKS], ElT[4 * ECHUNKS];   // 8.25KB  (E: 64 rows)
    // reduction scratch UNIONED onto E staging (dead after K-loop; KBARRIER
    // separates last tile read from first redv write). redv/redi: 128 rows x 2 wn.
    float* redv = (float*)&EhT[0];                          // 1KB of 4.1KB
    int*   redi = (int*)&ElT[0];                            // 1KB of 4.1KB

    const int tid = threadIdx.x;
    const int lane = tid & 63, wave = tid >> 6;
    const int wm = wave >> 1, wn = wave & 1;      // 2x2 wave grid; per-wave 64x32
    const int tx = lane & 15, qd = lane >> 4;
    const int bm = blockIdx.x & 127, bn = blockIdx.x >> 7;   // XCD swizzle: bm low
    const int m0 = bm * 128, c0 = bn * 64;

    // staging: thread t handles A rows (t>>2), (t>>2)+64 and E row (t>>2); kq=t&3
    const int srow = tid >> 2, skq = tid & 3;
    const _Float16* gA  = ah + (size_t)(m0 + srow) * DIM + skq * 8;
    const _Float16* gAl = al + (size_t)(m0 + srow) * DIM + skq * 8;
    const _Float16* gE  = eh + (size_t)(c0 + srow) * DIM + skq * 8;
    const _Float16* gEl = el + (size_t)(c0 + srow) * DIM + skq * 8;
    const int cw0 = skq * CHUNKS + srow, cw1 = cw0 + 64;    // A LDS chunk indices
    const int cwe = skq * ECHUNKS + srow;                   // E LDS chunk index

    floatx4 acc[4][2];
    #pragma unroll
    for (int i = 0; i < 4; ++i)
        #pragma unroll
        for (int j = 0; j < 2; ++j) acc[i][j] = (floatx4){0.f, 0.f, 0.f, 0.f};

    // one named staging set (rule #20: named regs, not runtime-indexed)
    half8 sA0, sA1, sL0, sL1, sE0, sF0;

    // prologue: tile0 -> LDS; tile1 -> regs, in flight across barrier + compute
    LOAD_SET(s, 0);
    STORE_SET(s);
    LOAD_SET(s, 32);

    #pragma unroll 1                               // spill guard
    for (int kt = 0; kt < 16; ++kt) {
        KBARRIER();                                // tile kt writes visible (lgkm only)
        COMPUTE();                                 // tile kt from LDS
        if (kt < 15) {
            KBARRIER();                            // all waves done READING tile kt
            STORE_SET(s);                          // tile kt+1 regs -> LDS
            if (kt < 14) { LOAD_SET(s, (kt + 2) * 32); }  // refill: in flight a full kt
        }
    }
    KBARRIER();                                    // tile reads done -> E LDS reusable

    // ---- epilogue: scores + argmin (identical arithmetic to passing rounds) ----
    float sqe_v[2];
    #pragma unroll
    for (int j = 0; j < 2; ++j) sqe_v[j] = esq[c0 + wn * 32 + j * 16 + tx];
    #pragma unroll
    for (int i = 0; i < 4; ++i) {
        #pragma unroll
        for (int r = 0; r < 4; ++r) {
            int rl = wm * 64 + i * 16 + qd * 4 + r;        // C/D: row = qd*4+reg
            float sx = xsq[m0 + rl];
            float bvv = FLT_MAX; int bii = 0x7fffffff;
            #pragma unroll
            for (int j = 0; j < 2; ++j) {
                float S = sx + sqe_v[j];                   // fl(sqx + sqe)
                float s = S - acc[i][j][r] * (1.0f / 67108864.0f);  // fl(S - 2m)
                int c = c0 + wn * 32 + j * 16 + tx;
                if (s < bvv || (s == bvv && c < bii)) { bvv = s; bii = c; }
            }
            #pragma unroll
            for (int md = 1; md < 16; md <<= 1) {
                float ov = __shfl_xor(bvv, md, 64);
                int   oc = __shfl_xor(bii, md, 64);
                if (ov < bvv || (ov == bvv && oc < bii)) { bvv = ov; bii = oc; }
            }
            if (tx == 0) { redv[rl * 2 + wn] = bvv; redi[rl * 2 + wn] = bii; }
        }
    }
    __syncthreads();
    if (tid < 128) {
        float v0 = redv[tid * 2 + 0], v1 = redv[tid * 2 + 1];
        int   i0 = redi[tid * 2 + 0], i1 = redi[tid * 2 + 1];
        float v = (v1 < v0) ? v1 : v0;            // tie -> wn0 (smaller col)
        int   ix = (v1 < v0) ? i1 : i0;
        // scores positive -> float bits monotonic; lexicographic (bits,idx) min
        // == np.argmin first-occurrence tie-break.
        unsigned long long pk = ((unsigned long long)__float_as_uint(v) << 32)
                              | (unsigned int)ix;
        atomicMin(&packed[m0 + tid], pk);
    }
}

// ---------------- kernel 3: indices + gather quantized + loss from scores ----------------
// loss = 1.25 * mean(min-score): the min score IS fl(||x-e||^2) to ~1e-4/row;
// summed error ~1e-7 << the output threshold. Saves re-reading A (33.5 MB).
// 1024 blocks x 16 rows (passed rounds 1-8): 256-block grid was 1 block/CU.
__global__ __launch_bounds__(256) void finalize_kernel(const float* __restrict__ E,
                                                       const unsigned long long* __restrict__ packed,
                                                       float* __restrict__ out) {
    float* q = out + 1;
    float* idxF = out + 1 + QELEMS;
    const int tid = threadIdx.x;
    const int r0 = blockIdx.x * 16;

    __shared__ int sidx[16];
    if (tid < 64) {                               // wave 0: unpack idx + score
        float sc = 0.f;
        if (tid < 16) {
            unsigned long long pk = packed[r0 + tid];
            int idx = (int)(unsigned int)(pk & 0xFFFFFFFFull);
            sc = __uint_as_float((unsigned int)(pk >> 32));
            sidx[tid] = idx;
            idxF[r0 + tid] = (float)idx;
        }
        #pragma unroll
        for (int off = 8; off; off >>= 1) sc += __shfl_down(sc, off, 16);
        if (tid == 0) atomicAdd(out, sc * (1.25f / (float)QELEMS));
    }
    __syncthreads();

    #pragma unroll 4
    for (int it = 0; it < 8; ++it) {              // 16 rows * 128 float4 = 2048 slots
        int flat = it * 256 + tid;
        int row = flat >> 7;
        int d4  = (flat & 127) * 4;
        int idx = sidx[row];
        float4 e = *(const float4*)(E + (size_t)idx * DIM + d4);
        *(float4*)(q + (size_t)(r0 + row) * DIM + d4) = e;
    }
}

extern "C" void kernel_launch(void* const* d_in, const int* in_sizes, int n_in,
                              void* d_out, int out_size, void* d_ws, size_t ws_size,
                              hipStream_t stream) {
    const float* A = (const float*)d_in[0];   // inputs (64,256,512)
    const float* E = (const float*)d_in[1];   // emb_weight (1024,512)
    float* out = (float*)d_out;

    unsigned long long* packed = (unsigned long long*)d_ws;     // 16384 u64
    float*    esq  = (float*)(packed + NROWS);                  // 1024
    float*    xsq  = esq + KC;                                  // 16384
    _Float16* eh   = (_Float16*)(xsq + NROWS);                  // 1024*512 (16B-aligned)
    _Float16* el   = eh + (size_t)KC * DIM;
    _Float16* ah   = el + (size_t)KC * DIM;                     // 16384*512
    _Float16* al   = ah + (size_t)NROWS * DIM;

    prep_kernel<<<NROWS / 4 + KC / 4, 256, 0, stream>>>(A, E, xsq, esq, ah, al, eh, el, packed, out);
    mfma_argmin_kernel<<<(NROWS / 128) * NSPLIT, 256, 0, stream>>>(
        ah, al, eh, el, esq, xsq, packed);
    finalize_kernel<<<NROWS / 16, 256, 0, stream>>>(E, packed, out);
}